// Round 7
// baseline (503.609 us; speedup 1.0000x reference)
//
#include <hip/hip_runtime.h>
#include <stdint.h>

#define B_ 64
#define T_ 2000
#define QD 1024
#define MD 512
#define AD 128
#define NF 32
#define KW 31
#define TT 16
#define NCHT 125    // total chunks (125*16 == 2000)
#define NCH 5       // chunks per block
#define GPB 25      // block-groups per batch row (25*5 == 125)
#define RSTRIDE 516 // row stride in floats: 512 + 4 (16B pad -> conflict-free phases)

typedef short bf16x8 __attribute__((ext_vector_type(8)));
typedef float f32x4 __attribute__((ext_vector_type(4)));

// s_waitcnt imm: vmcnt[3:0]|[15:14], expcnt[6:4]=7 (no wait), lgkmcnt[11:8]
#define WAITCNT(vm, lgkm) (((vm) & 15) | (7 << 4) | (((lgkm) & 15) << 8) | (((vm) >> 4) << 14))

__device__ __forceinline__ unsigned short f2bf(float f) {
    union { float f; uint32_t u; } v; v.f = f;
    uint32_t u = v.u;
    return (unsigned short)((u + 0x7FFFu + ((u >> 16) & 1u)) >> 16);
}

// ONE v_perm_b32: word = bf16_trunc(lo) | bf16_trunc(hi)<<16
__device__ __forceinline__ uint32_t pktrunc(float lo, float hi) {
    union { float f; uint32_t u; } a, c; a.f = lo; c.f = hi;
    return __builtin_amdgcn_perm(a.u, c.u, 0x03020706u);
}

__device__ __forceinline__ float fast_tanhf(float x) {
    x = fminf(15.f, fmaxf(-15.f, x));
    float e = __expf(2.f * x);
    return __fdividef(e - 1.f, e + 1.f);
}

// async 16B-per-lane DMA: LDS dest is wave-uniform base + lane*16
__device__ __forceinline__ void dma16(const float* src, void* lds_dst) {
    __builtin_amdgcn_global_load_lds(
        (const __attribute__((address_space(1))) void*)src,
        (__attribute__((address_space(3))) void*)lds_dst, 16, 0, 0);
}

// stage one 16x512 fp32 tile. R7: LANE-CONTIGUOUS source (identity granules,
// fully coalesced 1KB per instruction); LDS rows padded +16B (stride 2064B).
__device__ __forceinline__ void stage_tile(const float* __restrict__ rowbase,
                                           void* lds_base, int wave, int lane) {
    #pragma unroll
    for (int s8 = 0; s8 < 8; ++s8) {
        int seg = wave * 8 + s8;                 // 32 segments of 1KB
        int row = seg >> 1, half = seg & 1;
        dma16(rowbase + row * MD + (half * 64 + lane) * 4,
              (char*)lds_base + row * (RSTRIDE * 4) + half * 1024);
    }
}

// ---------------- prep1: pq partials (k-split) + pack Wm,Wloc to bf16 frags ----
__global__ __launch_bounds__(128) void prep1_kernel(
    const float* __restrict__ query, const float* __restrict__ Wq,
    const float* __restrict__ Wm, const float* __restrict__ Wloc,
    float* __restrict__ pqpart, unsigned short* __restrict__ wmp,
    unsigned short* __restrict__ wlp)
{
    int blk = blockIdx.x, tid = threadIdx.x;
    if (blk < 512) {                       // pq partial: b = blk>>3, k-slice = blk&7
        int b = blk >> 3, sl = blk & 7;
        const float* qq = query + b * QD + sl * 128;
        const float* wq = Wq + (size_t)(sl * 128) * AD + tid;
        float s = 0.f;
        #pragma unroll 4
        for (int d = 0; d < 128; ++d) s += qq[d] * wq[(size_t)d * AD];
        pqpart[(b * 8 + sl) * AD + tid] = s;
    } else if (blk < 528) {                // Wm -> B-frag pack (validated R3-R6)
        int kt = blk - 512;
        int nt = tid >> 4, c = tid & 15;
        for (int q = 0; q < 4; ++q)
            for (int j = 0; j < 8; ++j)
                wmp[(((kt * 8 + nt) * 64) + q * 16 + c) * 8 + j] =
                    f2bf(Wm[(kt * 32 + q * 8 + j) * AD + nt * 16 + c]);
    } else {                               // Wloc -> B-frag pack (K=32, one kt)
        int nt = tid >> 4, c = tid & 15;
        for (int q = 0; q < 4; ++q)
            for (int j = 0; j < 8; ++j)
                wlp[((nt * 64) + q * 16 + c) * 8 + j] =
                    f2bf(Wloc[(q * 8 + j) * AD + nt * 16 + c]);
    }
}

// ---------------- conv: location features -> bf16 MFMA A-frags, all chunks -----
__global__ __launch_bounds__(256) void conv_kernel(
    const float* __restrict__ awc, const float* __restrict__ kern,
    unsigned short* __restrict__ cfrag)
{
    const int ci = blockIdx.x, b = blockIdx.y;
    const int t0 = ci * TT;
    const int tid = threadIdx.x;
    const int f = tid & 31, tA = tid >> 5, tB = tA + 8;   // two rows per thread
    const float* a0p = awc + (b * 2 + 0) * T_;
    const float* a1p = awc + (b * 2 + 1) * T_;
    float sA = 0.f, sB = 0.f;
    #pragma unroll
    for (int k = 0; k < KW; ++k) {
        float k0 = kern[(k * 2 + 0) * NF + f];
        float k1 = kern[(k * 2 + 1) * NF + f];
        int xA = t0 + tA + k - 15, xB = t0 + tB + k - 15;
        float wA0 = (xA >= 0 && xA < T_) ? a0p[xA] : 0.f;
        float wA1 = (xA >= 0 && xA < T_) ? a1p[xA] : 0.f;
        float wB0 = (xB >= 0 && xB < T_) ? a0p[xB] : 0.f;
        float wB1 = (xB >= 0 && xB < T_) ? a1p[xB] : 0.f;
        sA = fmaf(wA0, k0, sA); sA = fmaf(wA1, k1, sA);
        sB = fmaf(wB0, k0, sB); sB = fmaf(wB1, k1, sB);
    }
    unsigned short* base = cfrag + (size_t)(b * NCHT + ci) * 64 * 8;
    base[((f >> 3) * 16 + tA) * 8 + (f & 7)] = f2bf(sA);
    base[((f >> 3) * 16 + tB) * 8 + (f & 7)] = f2bf(sB);
}

// ---------------- energy: pipelined DMA staging + MFMA + softmax + context -----
__global__ __launch_bounds__(256, 2) void energy_kernel(
    const float* __restrict__ mem, const float* __restrict__ V,
    const float* __restrict__ pqpart,
    const unsigned short* __restrict__ wmp, const unsigned short* __restrict__ wlp,
    const unsigned short* __restrict__ cfrag,
    float* __restrict__ p_ws, float* __restrict__ Lpart, float* __restrict__ ctxpart)
{
    const int g = blockIdx.x, b = blockIdx.y;
    const int tid = threadIdx.x, lane = tid & 63, wave = tid >> 6;
    const int c0 = g * NCH;
    const int q = lane >> 4, cx = lane & 15;
    const int nt0 = wave * 2;

    __shared__ __align__(16) float mem_s[2][TT * RSTRIDE];   // 66048 B, padded rows
    __shared__ __align__(16) float epart[TT][4];
    __shared__ float pex[TT];

    const float* memb = mem + (size_t)b * T_ * MD;

    // pq = tanh(sum of 8 k-split partials)
    const int a0 = nt0 * 16 + cx, a1 = a0 + 16;
    float pq0a = 0.f, pq1a = 0.f;
    #pragma unroll
    for (int sl = 0; sl < 8; ++sl) {
        pq0a += pqpart[(b * 8 + sl) * AD + a0];
        pq1a += pqpart[(b * 8 + sl) * AD + a1];
    }
    const float pq0 = fast_tanhf(pq0a), pq1 = fast_tanhf(pq1a);
    const float v0 = V[a0], v1 = V[a1];
    const bf16x8 wl0 = *(const bf16x8*)(wlp + ((nt0 + 0) * 64 + lane) * 8);
    const bf16x8 wl1 = *(const bf16x8*)(wlp + ((nt0 + 1) * 64 + lane) * 8);

    const unsigned short* cfb = cfrag + ((size_t)(b * NCHT + c0) * 64 + lane) * 8;
    bf16x8 af = *(const bf16x8*)cfb;      // conv A-frag, chunk 0
    bf16x8 af_next = af;

    // context accumulator: 4 consecutive d's, half the rows (parity h)
    f32x4 ctx = {};
    const int gq = tid & 127, h = tid >> 7;

    stage_tile(memb + (size_t)(c0 + 0) * TT * MD, &mem_s[0][0], wave, lane);

    for (int i = 0; i < NCH; ++i) {
        const int cb = i & 1;
        const int t0c = (c0 + i) * TT;

        // B1: tile i ready (its DMA had a full chunk of compute as lead time)
        __builtin_amdgcn_s_waitcnt(WAITCNT(0, 0));
        __builtin_amdgcn_s_barrier();

        // immediately refill the just-freed buffer -> full-chunk DMA lead time
        if (i + 1 < NCH) {
            stage_tile(memb + (size_t)(c0 + i + 1) * TT * MD,
                       &mem_s[(i + 1) & 1][0], wave, lane);
            af_next = *(const bf16x8*)(cfb + (size_t)(i + 1) * 64 * 8);
        }

        // MFMA: ploc (1 kt, regs) + pm (16 kt; A packed via single v_perm per word)
        f32x4 accl0 = {}, accl1 = {}, accm0 = {}, accm1 = {};
        accl0 = __builtin_amdgcn_mfma_f32_16x16x32_bf16(af, wl0, accl0, 0, 0, 0);
        accl1 = __builtin_amdgcn_mfma_f32_16x16x32_bf16(af, wl1, accl1, 0, 0, 0);
        {
            const float* tb = &mem_s[cb][0];
            #pragma unroll 4
            for (int kt = 0; kt < 16; ++kt) {
                int gr0 = kt * 8 + 2 * q;
                float4 x0 = *(const float4*)(tb + cx * RSTRIDE + (gr0 + 0) * 4);
                float4 x1 = *(const float4*)(tb + cx * RSTRIDE + (gr0 + 1) * 4);
                union { bf16x8 v; uint32_t w[4]; } u;
                u.w[0] = pktrunc(x0.x, x0.y); u.w[1] = pktrunc(x0.z, x0.w);
                u.w[2] = pktrunc(x1.x, x1.y); u.w[3] = pktrunc(x1.z, x1.w);
                bf16x8 b0 = *(const bf16x8*)(wmp + (((kt * 8 + nt0 + 0) * 64) + lane) * 8);
                bf16x8 b1 = *(const bf16x8*)(wmp + (((kt * 8 + nt0 + 1) * 64) + lane) * 8);
                accm0 = __builtin_amdgcn_mfma_f32_16x16x32_bf16(u.v, b0, accm0, 0, 0, 0);
                accm1 = __builtin_amdgcn_mfma_f32_16x16x32_bf16(u.v, b1, accm1, 0, 0, 0);
            }
        }

        // epilogue: e_t = sum_a tanh(pq + tanh(ploc) + tanh(pm)) * V[a]
        #pragma unroll
        for (int r = 0; r < 4; ++r) {
            int tl = q * 4 + r;
            float s = fast_tanhf(pq0 + fast_tanhf(accl0[r]) + fast_tanhf(accm0[r])) * v0
                    + fast_tanhf(pq1 + fast_tanhf(accl1[r]) + fast_tanhf(accm1[r])) * v1;
            s += __shfl_xor(s, 1);
            s += __shfl_xor(s, 2);
            s += __shfl_xor(s, 4);
            s += __shfl_xor(s, 8);
            if (cx == 0) epart[tl][wave] = s;
        }
        __builtin_amdgcn_s_waitcnt(WAITCNT(63, 0));   // lgkm only: DMA stays in flight
        __builtin_amdgcn_s_barrier();   // B2

        // p = exp(e)  (|e| <= sum|V| ~ 9: no max-subtraction needed)
        if (tid < TT) {
            float4 ep = *(const float4*)&epart[tid][0];
            float pv = __expf(ep.x + ep.y + ep.z + ep.w);
            pex[tid] = pv;
            p_ws[b * T_ + t0c + tid] = pv;
            float Ls = pv;
            Ls += __shfl_xor(Ls, 1);
            Ls += __shfl_xor(Ls, 2);
            Ls += __shfl_xor(Ls, 4);
            Ls += __shfl_xor(Ls, 8);
            if (tid == 0) Lpart[b * NCHT + c0 + i] = Ls;
        }
        __builtin_amdgcn_s_waitcnt(WAITCNT(63, 0));
        __builtin_amdgcn_s_barrier();   // B3

        // context: float4 per thread per row-pair from the padded fp32 tile
        {
            const float* tb = &mem_s[cb][0];
            #pragma unroll
            for (int r = 0; r < 8; ++r) {
                int row = r * 2 + h;
                float w = pex[row];
                float4 m4 = *(const float4*)(tb + row * RSTRIDE + gq * 4);
                ctx.x = fmaf(w, m4.x, ctx.x);
                ctx.y = fmaf(w, m4.y, ctx.y);
                ctx.z = fmaf(w, m4.z, ctx.z);
                ctx.w = fmaf(w, m4.w, ctx.w);
            }
        }
        af = af_next;
        // no tile-consumed barrier: next B1 (after all waves' context) frees the buffer
    }

    float* cp = ctxpart + ((size_t)((b * GPB + g) * 2 + h)) * MD + gq * 4;
    *(float4*)cp = *(float4*)&ctx;
}

// ---------------- finalize: L, scale ctx, write weights ------------------------
__global__ __launch_bounds__(256) void finalize_kernel(
    const float* __restrict__ p_ws, const float* __restrict__ Lpart,
    const float* __restrict__ ctxpart, float* __restrict__ out)
{
    int part = blockIdx.x, b = blockIdx.y, tid = threadIdx.x;
    __shared__ float ws4[4];
    float s = (tid < NCHT) ? Lpart[b * NCHT + tid] : 0.f;
    s += __shfl_xor(s, 1);  s += __shfl_xor(s, 2);
    s += __shfl_xor(s, 4);  s += __shfl_xor(s, 8);
    s += __shfl_xor(s, 16); s += __shfl_xor(s, 32);
    if ((tid & 63) == 0) ws4[tid >> 6] = s;
    __syncthreads();
    float invL = 1.f / (ws4[0] + ws4[1] + ws4[2] + ws4[3]);
    if (part == 4) {
        float c0 = 0.f, c1 = 0.f;
        const float* cpb = ctxpart + (size_t)(b * GPB * 2) * MD;
        for (int gg = 0; gg < GPB * 2; ++gg) {
            const float* cp = cpb + (size_t)gg * MD;
            c0 += cp[tid];
            c1 += cp[tid + 256];
        }
        out[b * MD + tid] = c0 * invL;
        out[b * MD + tid + 256] = c1 * invL;
    } else {
        int t0 = part * 500;
        for (int t = t0 + tid; t < t0 + 500; t += 256)
            out[B_ * MD + b * T_ + t] = p_ws[b * T_ + t] * invL;
    }
}

extern "C" void kernel_launch(void* const* d_in, const int* in_sizes, int n_in,
                              void* d_out, int out_size, void* d_ws, size_t ws_size,
                              hipStream_t stream) {
    const float* query  = (const float*)d_in[0];
    const float* memory = (const float*)d_in[1];
    const float* awc    = (const float*)d_in[2];
    const float* Wq     = (const float*)d_in[3];
    const float* Wm     = (const float*)d_in[4];
    const float* kern   = (const float*)d_in[5];
    const float* Wloc   = (const float*)d_in[6];
    const float* V      = (const float*)d_in[7];
    float* out = (float*)d_out;

    char* ws = (char*)d_ws;
    float*          pqpart = (float*)(ws + 0);                 // 262144
    unsigned short* wmp    = (unsigned short*)(ws + 262144);   // 131072
    unsigned short* wlp    = (unsigned short*)(ws + 393216);   // 8192
    unsigned short* cfrag  = (unsigned short*)(ws + 401408);   // 8192000
    float*          p_ws   = (float*)(ws + 8593408);           // 512000
    float*          Lpart  = (float*)(ws + 9105408);           // 32000
    float*          ctxp   = (float*)(ws + 9137408);           // 6553600

    prep1_kernel<<<529, 128, 0, stream>>>(query, Wq, Wm, Wloc, pqpart, wmp, wlp);
    conv_kernel<<<dim3(NCHT, B_), 256, 0, stream>>>(awc, kern, cfrag);
    energy_kernel<<<dim3(GPB, B_), 256, 0, stream>>>(
        memory, V, pqpart, wmp, wlp, cfrag, p_ws, Lpart, ctxp);
    finalize_kernel<<<dim3(5, B_), 256, 0, stream>>>(p_ws, Lpart, ctxp, out);
}